// Round 5
// baseline (198.807 us; speedup 1.0000x reference)
//
#include <hip/hip_runtime.h>

#define NN 64
#define BB 8
#define HH 64
#define WW 64
#define EE 513
#define EQF -0.1f
#define IMG 4096
#define CHW 12288

typedef unsigned short u16;
typedef __attribute__((ext_vector_type(8))) short bf16x8;
typedef __attribute__((ext_vector_type(4))) float f32x4;

// actsI: bf16 [node][b][padded_row 0..66][w 0..63][ci4]; rows 0,65,66 are zero pad
#define ROWS_P 67
#define B_STR (ROWS_P * 256)      // 17152 u16 per (n,b) image
#define N_STR (BB * B_STR)        // 137216 u16 per node

__device__ __forceinline__ u16 f2bf(float f) {
  union { float f; unsigned u; } c; c.f = f;
  return (u16)((c.u + 0x7fffu + ((c.u >> 16) & 1u)) >> 16);
}

__device__ __forceinline__ bf16x8 mk_a(uint2 v) {
  union { uint2 u; short4 s; } cv; cv.u = v;
  bf16x8 a;
  a[0] = cv.s.x; a[1] = cv.s.y; a[2] = cv.s.z; a[3] = cv.s.w;
  a[4] = 0; a[5] = 0; a[6] = 0; a[7] = 0;
  return a;
}

// ---------------- meta: CSR(+src resolve) + per-node bias sums + wfrag ----------------
__global__ __launch_bounds__(256) void meta_k(const float* __restrict__ conv_w,
                                              const float* __restrict__ conv_b,
                                              const int* __restrict__ src,
                                              const int* __restrict__ dst,
                                              u16* __restrict__ wfrag,
                                              int* __restrict__ csr_off,
                                              int2* __restrict__ csr2,
                                              float* __restrict__ nodeBias) {
  __shared__ int sdst[EE];
  __shared__ int ssrc[EE];
  __shared__ float sbias[EE * 3];
  __shared__ int scnt[NN];
  __shared__ int soff[NN + 1];
  int tid = threadIdx.x;
  if (blockIdx.x == 0) {
    for (int e = tid; e < EE; e += 256) { sdst[e] = dst[e]; ssrc[e] = src[e]; }
    for (int i = tid; i < EE * 3; i += 256) sbias[i] = conv_b[i];
    __syncthreads();
    if (tid < NN) {
      int c = 0;
      for (int e = 0; e < EE; ++e) c += (sdst[e] == tid) ? 1 : 0;
      scnt[tid] = c;
    }
    __syncthreads();
    if (tid == 0) {
      int s = 0;
      for (int n2 = 0; n2 < NN; ++n2) { soff[n2] = s; s += scnt[n2]; }
      soff[NN] = s;
    }
    __syncthreads();
    if (tid < NN) {
      int p = soff[tid];
      for (int e = 0; e < EE; ++e)
        if (sdst[e] == tid) { csr2[p] = make_int2(ssrc[e] * N_STR, e * 512); ++p; }
    }
    if (tid >= 64 && tid < 256) {
      int q = tid - 64;                // 0..191 = n*3+co
      int n = q / 3, co = q - n * 3;
      float s = 0.f;
      for (int e = 0; e < EE; ++e)
        if (sdst[e] == n) s += sbias[e * 3 + co];
      nodeBias[q] = s;
    }
    if (tid <= NN) csr_off[tid] = soff[tid];
  } else {
    int gid = (blockIdx.x - 1) * 256 + tid;
    if (gid < EE * 64) {
      int e = gid >> 6, l = gid & 63;
      int g = l >> 4, col = l & 15, co = col >> 2, kw = col & 3;
      u16 v[8];
      #pragma unroll
      for (int j = 0; j < 8; ++j) {
        float f = 0.0f;
        if (co < 3 && j < 3) f = conv_w[e * 144 + co * 48 + j * 16 + g * 4 + kw];
        v[j] = f2bf(f);
      }
      uint4 pk;
      pk.x = (unsigned)v[0] | ((unsigned)v[1] << 16);
      pk.y = (unsigned)v[2] | ((unsigned)v[3] << 16);
      pk.z = (unsigned)v[4] | ((unsigned)v[5] << 16);
      pk.w = (unsigned)v[6] | ((unsigned)v[7] << 16);
      *(uint4*)(wfrag + (size_t)gid * 8) = pk;
    }
  }
}

// ---------------- acts = sigmoid(states+noise) -> padded ci-interleaved bf16 ----------------
__global__ __launch_bounds__(256) void prep_k(const float* __restrict__ states,
                                              const float* __restrict__ noise,
                                              u16* __restrict__ actsI,
                                              float* __restrict__ out) {
  int idx = blockIdx.x * 256 + threadIdx.x;      // 65*8*64*16 = 532480 exact
  int w4 = idx & 15, h = (idx >> 4) & 63, b = (idx >> 10) & 7, n = idx >> 13;
  int pbase = (n * 8 + b) * CHW + h * 64 + w4 * 4;
  float4 s0 = *(const float4*)(states + pbase);
  float4 s1 = *(const float4*)(states + pbase + IMG);
  float4 s2 = *(const float4*)(states + pbase + 2 * IMG);
  float4 z0 = *(const float4*)(noise + pbase);
  float4 z1 = *(const float4*)(noise + pbase + IMG);
  float4 z2 = *(const float4*)(noise + pbase + 2 * IMG);
  float a0[4], a1[4], a2[4];
  #pragma unroll
  for (int p = 0; p < 4; ++p) {
    float v0 = ((const float*)&s0)[p] + ((const float*)&z0)[p];
    float v1 = ((const float*)&s1)[p] + ((const float*)&z1)[p];
    float v2 = ((const float*)&s2)[p] + ((const float*)&z2)[p];
    a0[p] = 1.0f / (1.0f + __expf(-v0));
    a1[p] = 1.0f / (1.0f + __expf(-v1));
    a2[p] = 1.0f / (1.0f + __expf(-v2));
  }
  uint4 q0, q1;
  q0.x = (unsigned)f2bf(a0[0]) | ((unsigned)f2bf(a1[0]) << 16);
  q0.y = (unsigned)f2bf(a2[0]);
  q0.z = (unsigned)f2bf(a0[1]) | ((unsigned)f2bf(a1[1]) << 16);
  q0.w = (unsigned)f2bf(a2[1]);
  q1.x = (unsigned)f2bf(a0[2]) | ((unsigned)f2bf(a1[2]) << 16);
  q1.y = (unsigned)f2bf(a2[2]);
  q1.z = (unsigned)f2bf(a0[3]) | ((unsigned)f2bf(a1[3]) << 16);
  q1.w = (unsigned)f2bf(a2[3]);
  u16* dp = actsI + (size_t)((n * 8 + b) * ROWS_P + (h + 1)) * 256 + w4 * 16;
  *(uint4*)dp = q0;
  *(uint4*)(dp + 8) = q1;
  // zero pad rows (SAME pad (1,2): padded rows 0, 65, 66)
  uint4 zz; zz.x = 0u; zz.y = 0u; zz.z = 0u; zz.w = 0u;
  if (h == 0) {
    u16* zp = actsI + (size_t)((n * 8 + b) * ROWS_P + 0) * 256 + w4 * 16;
    *(uint4*)zp = zz; *(uint4*)(zp + 8) = zz;
  }
  if (h == 63) {
    u16* zp = actsI + (size_t)((n * 8 + b) * ROWS_P + 65) * 256 + w4 * 16;
    *(uint4*)zp = zz; *(uint4*)(zp + 8) = zz;
    zp += 256;
    *(uint4*)zp = zz; *(uint4*)(zp + 8) = zz;
  }
  if (n == NN) {   // virtual node: out = states (agg is 0 there)
    *(float4*)(out + pbase) = s0;
    *(float4*)(out + pbase + IMG) = s1;
    *(float4*)(out + pbase + 2 * IMG) = s2;
  }
}

// ---------------- direct-load MFMA conv + epilogue (no LDS in loop, no barriers) ----------------
__global__ __launch_bounds__(64, 4) void conv_k(const float* __restrict__ states,
                                                const float* __restrict__ res,
                                                const u16* __restrict__ actsI,
                                                const u16* __restrict__ wfrag,
                                                const int* __restrict__ csr_off,
                                                const int2* __restrict__ csr2,
                                                const float* __restrict__ nodeBias,
                                                float* __restrict__ out) {
  __shared__ __align__(16) float zb[1664];   // [2][64][13] f32, per-wave block

  const int lane = threadIdx.x & 63;
  const int gw = blockIdx.x;                 // 16384 waves
  const int ht2 = gw & 31, b = (gw >> 5) & 7, n = gw >> 8;
  const int r0 = ht2 * 2;

  // per-lane A-fragment offsets (u16 units), constant across edges
  const int g = lane >> 4, px = lane & 15;
  int aoff[8];
  #pragma unroll
  for (int h2 = 0; h2 < 2; ++h2)
    #pragma unroll
    for (int t = 0; t < 4; ++t)
      aoff[h2 * 4 + t] = b * B_STR + (r0 + h2 + g) * 256 + (t * 16 + px) * 4;

  f32x4 acc[8];
  #pragma unroll
  for (int j = 0; j < 8; ++j) { acc[j][0] = 0.f; acc[j][1] = 0.f; acc[j][2] = 0.f; acc[j][3] = 0.f; }

  const int e0 = csr_off[n];
  const int cnt = csr_off[n + 1] - e0;

  uint2 A0, A1, A2, A3, A4, A5, A6, A7; bf16x8 Aw;
  uint2 B0, B1, B2, B3, B4, B5, B6, B7; bf16x8 Bw;
  uint2 C0, C1, C2, C3, C4, C5, C6, C7; bf16x8 Cw;

#define LOADSET(S0,S1,S2,S3,S4,S5,S6,S7,SW,IDX) do {                          \
    int2 c_ = csr2[IDX];                                                      \
    int cx_ = __builtin_amdgcn_readfirstlane(c_.x);                           \
    int cy_ = __builtin_amdgcn_readfirstlane(c_.y);                           \
    const u16* ab_ = actsI + cx_;                                             \
    S0 = *(const uint2*)(ab_ + aoff[0]);                                      \
    S1 = *(const uint2*)(ab_ + aoff[1]);                                      \
    S2 = *(const uint2*)(ab_ + aoff[2]);                                      \
    S3 = *(const uint2*)(ab_ + aoff[3]);                                      \
    S4 = *(const uint2*)(ab_ + aoff[4]);                                      \
    S5 = *(const uint2*)(ab_ + aoff[5]);                                      \
    S6 = *(const uint2*)(ab_ + aoff[6]);                                      \
    S7 = *(const uint2*)(ab_ + aoff[7]);                                      \
    SW = *(const bf16x8*)(wfrag + cy_ + lane * 8);                            \
  } while (0)

#define STEP(S0,S1,S2,S3,S4,S5,S6,S7,SW) do {                                 \
    acc[0] = __builtin_amdgcn_mfma_f32_16x16x32_bf16(mk_a(S0), SW, acc[0], 0, 0, 0); \
    acc[1] = __builtin_amdgcn_mfma_f32_16x16x32_bf16(mk_a(S1), SW, acc[1], 0, 0, 0); \
    acc[2] = __builtin_amdgcn_mfma_f32_16x16x32_bf16(mk_a(S2), SW, acc[2], 0, 0, 0); \
    acc[3] = __builtin_amdgcn_mfma_f32_16x16x32_bf16(mk_a(S3), SW, acc[3], 0, 0, 0); \
    acc[4] = __builtin_amdgcn_mfma_f32_16x16x32_bf16(mk_a(S4), SW, acc[4], 0, 0, 0); \
    acc[5] = __builtin_amdgcn_mfma_f32_16x16x32_bf16(mk_a(S5), SW, acc[5], 0, 0, 0); \
    acc[6] = __builtin_amdgcn_mfma_f32_16x16x32_bf16(mk_a(S6), SW, acc[6], 0, 0, 0); \
    acc[7] = __builtin_amdgcn_mfma_f32_16x16x32_bf16(mk_a(S7), SW, acc[7], 0, 0, 0); \
  } while (0)

  if (cnt > 0) LOADSET(A0,A1,A2,A3,A4,A5,A6,A7,Aw, e0);
  if (cnt > 1) LOADSET(B0,B1,B2,B3,B4,B5,B6,B7,Bw, e0 + 1);
  if (cnt > 2) LOADSET(C0,C1,C2,C3,C4,C5,C6,C7,Cw, e0 + 2);
  for (int i = 0; i < cnt; i += 3) {
    STEP(A0,A1,A2,A3,A4,A5,A6,A7,Aw);
    if (i + 3 < cnt) LOADSET(A0,A1,A2,A3,A4,A5,A6,A7,Aw, e0 + i + 3);
    if (i + 1 < cnt) {
      STEP(B0,B1,B2,B3,B4,B5,B6,B7,Bw);
      if (i + 4 < cnt) LOADSET(B0,B1,B2,B3,B4,B5,B6,B7,Bw, e0 + i + 4);
    }
    if (i + 2 < cnt) {
      STEP(C0,C1,C2,C3,C4,C5,C6,C7,Cw);
      if (i + 5 < cnt) LOADSET(C0,C1,C2,C3,C4,C5,C6,C7,Cw, e0 + i + 5);
    }
  }

  // ---- epilogue ----
  float sreg[6], rreg[6]; int obase[6];
  #pragma unroll
  for (int h2 = 0; h2 < 2; ++h2)
    #pragma unroll
    for (int co = 0; co < 3; ++co) {
      int ix = h2 * 3 + co;
      obase[ix] = ((n * 8 + b) * 3 + co) * IMG + (r0 + h2) * 64 + lane;
      sreg[ix] = states[obase[ix]];
      rreg[ix] = res[obase[ix]];
    }

  const int col = lane & 15, gg = lane >> 4;
  if (col < 12) {
    #pragma unroll
    for (int h2 = 0; h2 < 2; ++h2)
      #pragma unroll
      for (int t = 0; t < 4; ++t)
        #pragma unroll
        for (int r = 0; r < 4; ++r)
          zb[(h2 * 64 + t * 16 + gg * 4 + r) * 13 + col] = acc[h2 * 4 + t][r];
  }
  // same-wave LDS RAW: compiler inserts lgkmcnt; no barrier needed (1 wave/block)
  float bco0 = nodeBias[n * 3 + 0];
  float bco1 = nodeBias[n * 3 + 1];
  float bco2 = nodeBias[n * 3 + 2];
  #pragma unroll
  for (int h2 = 0; h2 < 2; ++h2) {
    #pragma unroll
    for (int co = 0; co < 3; ++co) {
      float y = (co == 0) ? bco0 : ((co == 1) ? bco1 : bco2);
      #pragma unroll
      for (int kw = 0; kw < 4; ++kw) {
        int wp = lane + kw - 1;
        if (wp >= 0 && wp < 64) y += zb[(h2 * 64 + wp) * 13 + co * 4 + kw];
      }
      int ix = h2 * 3 + co;
      float st = sreg[ix];
      out[obase[ix]] = st + fabsf(rreg[ix]) * (EQF - st) + y;
    }
  }
}

extern "C" void kernel_launch(void* const* d_in, const int* in_sizes, int n_in,
                              void* d_out, int out_size, void* d_ws, size_t ws_size,
                              hipStream_t stream) {
  const float* states = (const float*)d_in[0];
  const float* noise  = (const float*)d_in[1];
  const float* conv_w = (const float*)d_in[2];
  const float* conv_b = (const float*)d_in[3];
  const float* res    = (const float*)d_in[4];
  const int*   src    = (const int*)d_in[5];
  const int*   dst    = (const int*)d_in[6];
  float* out = (float*)d_out;

  u16* actsI = (u16*)d_ws;                                   // 65*137216 u16 = 17,838,080 B
  u16* wfrag = (u16*)((char*)d_ws + 17838080);               //    525,312 B -> ends 18,363,392
  int* csr_off = (int*)((char*)d_ws + 18363392);             // 80 ints -> ends 18,363,712
  int2* csr2 = (int2*)((char*)d_ws + 18363712);              // 513*8 B -> ends 18,367,816
  float* nodeBias = (float*)((char*)d_ws + 18367816);        // 192 floats

  meta_k<<<130, 256, 0, stream>>>(conv_w, conv_b, src, dst, wfrag, csr_off, csr2, nodeBias);
  prep_k<<<2080, 256, 0, stream>>>(states, noise, actsI, out);
  conv_k<<<16384, 64, 0, stream>>>(states, res, actsI, wfrag, csr_off, csr2, nodeBias, out);
}

// Round 6
// 123.162 us; speedup vs baseline: 1.6142x; 1.6142x over previous
//
#include <hip/hip_runtime.h>

#define NN 64
#define BB 8
#define HH 64
#define WW 64
#define EE 513
#define EQF -0.1f
#define IMG 4096
#define CHW 12288

typedef unsigned short u16;
typedef __attribute__((ext_vector_type(8))) short bf16x8;
typedef __attribute__((ext_vector_type(4))) float f32x4;

// actsI: bf16 [node][b][padded_row 0..66][w 0..63][ci4]; rows 0,65,66 zero
#define ROWS_P 67
#define B_STR (ROWS_P * 256)      // 17152 u16 per (n,b) image
#define N_STR (BB * B_STR)        // 137216 u16 per node
#define MAXP 288                  // max total pairs = (513+63)/2 rounded up

__device__ __forceinline__ u16 f2bf(float f) {
  union { float f; unsigned u; } c; c.f = f;
  return (u16)((c.u + 0x7fffu + ((c.u >> 16) & 1u)) >> 16);
}

__device__ __forceinline__ bf16x8 mk_a2(uint2 lo, uint2 hi) {
  union { uint4 u; bf16x8 v; } c;
  c.u.x = lo.x; c.u.y = lo.y; c.u.z = hi.x; c.u.w = hi.y;
  return c.v;
}

// ---------------- meta1: CSR -> edge PAIRS + per-node bias sums ----------------
__global__ __launch_bounds__(256) void meta1_k(const float* __restrict__ conv_b,
                                               const int* __restrict__ src,
                                               const int* __restrict__ dst,
                                               int* __restrict__ pairOff,
                                               int4* __restrict__ csr3,
                                               float* __restrict__ nodeBias) {
  __shared__ int sdst[EE];
  __shared__ int ssrc[EE];
  __shared__ float sbias[EE * 3];
  __shared__ int scnt[NN];
  __shared__ int soff[NN + 1];
  int tid = threadIdx.x;
  for (int e = tid; e < EE; e += 256) { sdst[e] = dst[e]; ssrc[e] = src[e]; }
  for (int i = tid; i < EE * 3; i += 256) sbias[i] = conv_b[i];
  __syncthreads();
  if (tid < NN) {
    int c = 0;
    for (int e = 0; e < EE; ++e) c += (sdst[e] == tid) ? 1 : 0;
    scnt[tid] = (c + 1) >> 1;          // pair count
  }
  __syncthreads();
  if (tid == 0) {
    int s = 0;
    for (int n2 = 0; n2 < NN; ++n2) { soff[n2] = s; s += scnt[n2]; }
    soff[NN] = s;
  }
  __syncthreads();
  if (tid < NN) {
    int q = soff[tid], prev = -1;
    for (int e = 0; e < EE; ++e) {
      if (sdst[e] == tid) {
        if (prev < 0) prev = e;
        else { csr3[q] = make_int4(ssrc[prev] * N_STR, ssrc[e] * N_STR, prev, e); ++q; prev = -1; }
      }
    }
    if (prev >= 0) { csr3[q] = make_int4(ssrc[prev] * N_STR, ssrc[prev] * N_STR, prev, -1); ++q; }
  }
  if (tid >= 64 && tid < 256) {
    int q = tid - 64;                  // 0..191 = n*3+co
    int n = q / 3, co = q - n * 3;
    float s = 0.f;
    for (int e = 0; e < EE; ++e)
      if (sdst[e] == n) s += sbias[e * 3 + co];
    nodeBias[q] = s;
  }
  if (tid <= NN) pairOff[tid] = soff[tid];
}

// ---------------- meta2: build paired B-fragments wpair[q][lane][8] ----------------
__global__ __launch_bounds__(256) void wpair_k(const float* __restrict__ conv_w,
                                               const int4* __restrict__ csr3,
                                               const int* __restrict__ pairOff,
                                               u16* __restrict__ wpair) {
  int gid = blockIdx.x * 256 + threadIdx.x;
  int q = gid >> 6, l = gid & 63;
  if (q >= pairOff[NN]) return;
  int4 c = csr3[q];
  int g = l >> 4, col = l & 15, co = col >> 2, kw = col & 3;
  int e = (g < 2) ? c.z : c.w;
  u16 v[8];
  #pragma unroll
  for (int j = 0; j < 8; ++j) {
    int kh = 2 * (g & 1) + (j >> 2), ci = j & 3;
    float f = 0.0f;
    if (e >= 0 && co < 3 && ci < 3) f = conv_w[e * 144 + co * 48 + ci * 16 + kh * 4 + kw];
    v[j] = f2bf(f);
  }
  uint4 pk;
  pk.x = (unsigned)v[0] | ((unsigned)v[1] << 16);
  pk.y = (unsigned)v[2] | ((unsigned)v[3] << 16);
  pk.z = (unsigned)v[4] | ((unsigned)v[5] << 16);
  pk.w = (unsigned)v[6] | ((unsigned)v[7] << 16);
  *(uint4*)(wpair + (size_t)q * 512 + l * 8) = pk;
}

// ---------------- acts = sigmoid(states+noise) -> padded ci-interleaved bf16 ----------------
__global__ __launch_bounds__(256) void prep_k(const float* __restrict__ states,
                                              const float* __restrict__ noise,
                                              u16* __restrict__ actsI,
                                              float* __restrict__ out) {
  int idx = blockIdx.x * 256 + threadIdx.x;      // 65*8*64*16 = 532480 exact
  int w4 = idx & 15, h = (idx >> 4) & 63, b = (idx >> 10) & 7, n = idx >> 13;
  int pbase = (n * 8 + b) * CHW + h * 64 + w4 * 4;
  float4 s0 = *(const float4*)(states + pbase);
  float4 s1 = *(const float4*)(states + pbase + IMG);
  float4 s2 = *(const float4*)(states + pbase + 2 * IMG);
  float4 z0 = *(const float4*)(noise + pbase);
  float4 z1 = *(const float4*)(noise + pbase + IMG);
  float4 z2 = *(const float4*)(noise + pbase + 2 * IMG);
  float a0[4], a1[4], a2[4];
  #pragma unroll
  for (int p = 0; p < 4; ++p) {
    float v0 = ((const float*)&s0)[p] + ((const float*)&z0)[p];
    float v1 = ((const float*)&s1)[p] + ((const float*)&z1)[p];
    float v2 = ((const float*)&s2)[p] + ((const float*)&z2)[p];
    a0[p] = 1.0f / (1.0f + __expf(-v0));
    a1[p] = 1.0f / (1.0f + __expf(-v1));
    a2[p] = 1.0f / (1.0f + __expf(-v2));
  }
  uint4 q0, q1;
  q0.x = (unsigned)f2bf(a0[0]) | ((unsigned)f2bf(a1[0]) << 16);
  q0.y = (unsigned)f2bf(a2[0]);
  q0.z = (unsigned)f2bf(a0[1]) | ((unsigned)f2bf(a1[1]) << 16);
  q0.w = (unsigned)f2bf(a2[1]);
  q1.x = (unsigned)f2bf(a0[2]) | ((unsigned)f2bf(a1[2]) << 16);
  q1.y = (unsigned)f2bf(a2[2]);
  q1.z = (unsigned)f2bf(a0[3]) | ((unsigned)f2bf(a1[3]) << 16);
  q1.w = (unsigned)f2bf(a2[3]);
  u16* dp = actsI + (size_t)((n * 8 + b) * ROWS_P + (h + 1)) * 256 + w4 * 16;
  *(uint4*)dp = q0;
  *(uint4*)(dp + 8) = q1;
  uint4 zz; zz.x = 0u; zz.y = 0u; zz.z = 0u; zz.w = 0u;
  if (h == 0) {
    u16* zp = actsI + (size_t)((n * 8 + b) * ROWS_P + 0) * 256 + w4 * 16;
    *(uint4*)zp = zz; *(uint4*)(zp + 8) = zz;
  }
  if (h == 63) {
    u16* zp = actsI + (size_t)((n * 8 + b) * ROWS_P + 65) * 256 + w4 * 16;
    *(uint4*)zp = zz; *(uint4*)(zp + 8) = zz;
    zp += 256;
    *(uint4*)zp = zz; *(uint4*)(zp + 8) = zz;
  }
  if (n == NN) {   // virtual node: out = states
    *(float4*)(out + pbase) = s0;
    *(float4*)(out + pbase + IMG) = s1;
    *(float4*)(out + pbase + 2 * IMG) = s2;
  }
}

// ---------------- paired-edge direct-load MFMA conv + epilogue ----------------
__global__ __launch_bounds__(256, 4) void conv_k(const float* __restrict__ states,
                                                 const float* __restrict__ res,
                                                 const u16* __restrict__ actsI,
                                                 const u16* __restrict__ wpair,
                                                 const int* __restrict__ pairOff,
                                                 const int4* __restrict__ csr3,
                                                 const float* __restrict__ nodeBias,
                                                 float* __restrict__ out) {
  __shared__ __align__(16) float zbAll[4 * 1664];   // per-wave [2][64][13] f32

  const int tid = threadIdx.x, lane = tid & 63, wid = tid >> 6;
  const int gw = blockIdx.x * 4 + wid;              // 16384 waves
  const int ht2 = gw & 31, b = (gw >> 5) & 7, n = gw >> 8;
  const int r0 = ht2 * 2;

  const int g = lane >> 4, px = lane & 15;
  // per-lane invariant u16 offset: b image + within-pair kh block + pixel
  const int inv = b * B_STR + (g & 1) * 512 + px * 4 + r0 * 256;

  f32x4 acc[8];
  #pragma unroll
  for (int j = 0; j < 8; ++j) { acc[j][0] = 0.f; acc[j][1] = 0.f; acc[j][2] = 0.f; acc[j][3] = 0.f; }

  const int p0 = pairOff[n];
  const int P  = pairOff[n + 1] - p0;

  uint2 SA[16]; bf16x8 WA;
  uint2 SB[16]; bf16x8 WB;

  // LOADSET: 16 uint2 A-loads off one base + const imm, 1 wpair load
#define LOADSET(S, W, C, Q) do {                                              \
    int sel_ = (lane < 32) ? (C).x : (C).y;                                   \
    const u16* bp_ = actsI + (sel_ + inv);                                    \
    _Pragma("unroll")                                                         \
    for (int h2_ = 0; h2_ < 2; ++h2_)                                         \
      _Pragma("unroll")                                                       \
      for (int t_ = 0; t_ < 4; ++t_) {                                        \
        S[(h2_ * 4 + t_) * 2 + 0] = *(const uint2*)(bp_ + h2_ * 256 + t_ * 64);        \
        S[(h2_ * 4 + t_) * 2 + 1] = *(const uint2*)(bp_ + h2_ * 256 + t_ * 64 + 256);  \
      }                                                                       \
    W = *(const bf16x8*)(wpair + (size_t)(Q) * 512 + lane * 8);               \
  } while (0)

#define STEP(S, W) do {                                                       \
    _Pragma("unroll")                                                         \
    for (int f_ = 0; f_ < 8; ++f_)                                            \
      acc[f_] = __builtin_amdgcn_mfma_f32_16x16x32_bf16(                      \
          mk_a2(S[f_ * 2], S[f_ * 2 + 1]), W, acc[f_], 0, 0, 0);              \
  } while (0)

  int4 cA, cB;
  if (P > 0) { cA = csr3[p0];     LOADSET(SA, WA, cA, p0); }
  if (P > 1) { cB = csr3[p0 + 1]; LOADSET(SB, WB, cB, p0 + 1); }
  for (int i = 0; i < P; i += 2) {
    int4 cN;
    if (i + 2 < P) cN = csr3[p0 + i + 2];          // uniform -> s_load, early
    STEP(SA, WA);
    if (i + 2 < P) { cA = cN; LOADSET(SA, WA, cA, p0 + i + 2); }
    if (i + 1 < P) {
      int4 cM;
      if (i + 3 < P) cM = csr3[p0 + i + 3];
      STEP(SB, WB);
      if (i + 3 < P) { cB = cM; LOADSET(SB, WB, cB, p0 + i + 3); }
    }
  }

  // ---- epilogue: zbuf kw-combine + resistive update ----
  float* zb = zbAll + wid * 1664;   // [2][64][13]
  const int col = lane & 15;
  if (col < 12) {
    #pragma unroll
    for (int h2 = 0; h2 < 2; ++h2)
      #pragma unroll
      for (int t = 0; t < 4; ++t)
        #pragma unroll
        for (int r = 0; r < 4; ++r)
          zb[(h2 * 64 + t * 16 + g * 4 + r) * 13 + col] = acc[h2 * 4 + t][r];
  }
  float bco0 = nodeBias[n * 3 + 0];
  float bco1 = nodeBias[n * 3 + 1];
  float bco2 = nodeBias[n * 3 + 2];
  #pragma unroll
  for (int h2 = 0; h2 < 2; ++h2) {
    #pragma unroll
    for (int co = 0; co < 3; ++co) {
      float y = (co == 0) ? bco0 : ((co == 1) ? bco1 : bco2);
      #pragma unroll
      for (int kw = 0; kw < 4; ++kw) {
        int wp = lane + kw - 1;
        if (wp >= 0 && wp < 64) y += zb[(h2 * 64 + wp) * 13 + co * 4 + kw];
      }
      int o = ((n * 8 + b) * 3 + co) * IMG + (r0 + h2) * 64 + lane;
      float st = states[o];
      out[o] = st + fabsf(res[o]) * (EQF - st) + y;
    }
  }
}

extern "C" void kernel_launch(void* const* d_in, const int* in_sizes, int n_in,
                              void* d_out, int out_size, void* d_ws, size_t ws_size,
                              hipStream_t stream) {
  const float* states = (const float*)d_in[0];
  const float* noise  = (const float*)d_in[1];
  const float* conv_w = (const float*)d_in[2];
  const float* conv_b = (const float*)d_in[3];
  const float* res    = (const float*)d_in[4];
  const int*   src    = (const int*)d_in[5];
  const int*   dst    = (const int*)d_in[6];
  float* out = (float*)d_out;

  u16* actsI = (u16*)d_ws;                                   // 17,838,080 B
  u16* wpair = (u16*)((char*)d_ws + 17838080);               // 288 KiB -> ends 18,132,992
  int4* csr3 = (int4*)((char*)d_ws + 18132992);              // 4,608 B -> ends 18,137,600
  int* pairOff = (int*)((char*)d_ws + 18137600);             // 320 B -> ends 18,137,920
  float* nodeBias = (float*)((char*)d_ws + 18137920);        // 768 B

  meta1_k<<<1, 256, 0, stream>>>(conv_b, src, dst, pairOff, csr3, nodeBias);
  wpair_k<<<(MAXP * 64) / 256, 256, 0, stream>>>(conv_w, csr3, pairOff, wpair);
  prep_k<<<2080, 256, 0, stream>>>(states, noise, actsI, out);
  conv_k<<<4096, 256, 0, stream>>>(states, res, actsI, wpair, pairOff, csr3, nodeBias, out);
}

// Round 7
// 53.803 us; speedup vs baseline: 3.6951x; 2.2891x over previous
//
#include <hip/hip_runtime.h>

#define NN 64
#define BB 8
#define HH 64
#define WW 64
#define EE 513
#define EQF -0.1f
#define IMG 4096
#define CHW 12288

typedef unsigned short u16;
typedef __attribute__((ext_vector_type(8))) short bf16x8;
typedef __attribute__((ext_vector_type(4))) float f32x4;

// actsI: bf16 [node][b][padded_row 0..66][w 0..63][ci4]; rows 0,65,66 zero
#define ROWS_P 67
#define B_STR (ROWS_P * 256)      // 17152 u16 per (n,b) image
#define N_STR (BB * B_STR)        // 137216 u16 per node

#define TROW_B 528                // LDS tile row stride (bytes), 16B aligned
#define TILE_B (19 * TROW_B)      // 10032 B per buffer
#define NPIECE 608                // 19 rows * 32 x 16B pieces

__device__ __forceinline__ u16 f2bf(float f) {
  union { float f; unsigned u; } c; c.f = f;
  return (u16)((c.u + 0x7fffu + ((c.u >> 16) & 1u)) >> 16);
}

// ============ fused pre-kernel: block0=CSR, blocks1-65=wfrag, rest=prep ============
__global__ __launch_bounds__(512) void pre_k(const float* __restrict__ conv_w,
                                             const float* __restrict__ conv_b,
                                             const int* __restrict__ src,
                                             const int* __restrict__ dst,
                                             const float* __restrict__ states,
                                             const float* __restrict__ noise,
                                             u16* __restrict__ actsI,
                                             u16* __restrict__ wfrag,
                                             int* __restrict__ csr_off,
                                             int2* __restrict__ csr2,
                                             float* __restrict__ nodeBias,
                                             float* __restrict__ out) {
  __shared__ int sdst[EE];
  __shared__ int ssrc[EE];
  __shared__ int swcnt[8][64];
  __shared__ int spw[8][64];
  __shared__ int soffs[NN + 1];
  __shared__ int slist[EE];
  const int tid = threadIdx.x;
  const int bid = blockIdx.x;

  if (bid == 0) {
    // ---- parallel CSR build (deterministic: preserves edge order) ----
    for (int e = tid; e < EE; e += 512) { sdst[e] = dst[e]; ssrc[e] = src[e]; }
    __syncthreads();
    const int wv = tid >> 6, l = tid & 63;
    const int d = sdst[tid];          // edge = tid (0..511); edge 512 special-cased
    int rank = 0, cnt = 0;
    for (int i = 0; i < 64; ++i) {
      int di = __shfl(d, i, 64);
      rank += (di == d && i < l) ? 1 : 0;
      cnt  += (di == l) ? 1 : 0;
    }
    swcnt[wv][l] = cnt;               // count of node l within wave wv
    __syncthreads();
    if (tid < 64) {
      int s = 0;
      #pragma unroll
      for (int w2 = 0; w2 < 8; ++w2) { spw[w2][tid] = s; s += swcnt[w2][tid]; }
      int tot = s + ((sdst[512] == tid) ? 1 : 0);
      int scan = tot;
      #pragma unroll
      for (int ofs = 1; ofs < 64; ofs <<= 1) {
        int v = __shfl_up(scan, ofs, 64);
        if (tid >= ofs) scan += v;
      }
      soffs[tid] = scan - tot;        // exclusive offset
      if (tid == 63) soffs[64] = scan;
    }
    __syncthreads();
    slist[soffs[d] + spw[wv][d] + rank] = tid;
    if (tid == 0) { int d5 = sdst[512]; slist[soffs[d5 + 1] - 1] = 512; }  // 512 is last
    __syncthreads();
    if (tid <= NN) csr_off[tid] = soffs[tid];
    for (int q = tid; q < EE; q += 512) {
      int ee = slist[q];
      csr2[q] = make_int2(ssrc[ee] * N_STR, ee * 512);
    }
    if (tid < 192) {
      int n = tid / 3, co = tid - n * 3;
      float s = 0.f;
      for (int q = soffs[n]; q < soffs[n + 1]; ++q)
        s += conv_b[slist[q] * 3 + co];
      nodeBias[tid] = s;
    }
  } else if (bid <= 65) {
    // ---- per-edge B-fragments: wfrag[e][lane(g,col)][j] = W[co][ci=j][kh=g][kw] ----
    int gid = (bid - 1) * 512 + tid;
    if (gid < EE * 64) {
      int e = gid >> 6, l = gid & 63;
      int g = l >> 4, col = l & 15, co = col >> 2, kw = col & 3;
      u16 v[8];
      #pragma unroll
      for (int j = 0; j < 8; ++j) {
        float f = 0.0f;
        if (co < 3 && j < 3) f = conv_w[e * 144 + co * 48 + j * 16 + g * 4 + kw];
        v[j] = f2bf(f);
      }
      uint4 pk;
      pk.x = (unsigned)v[0] | ((unsigned)v[1] << 16);
      pk.y = (unsigned)v[2] | ((unsigned)v[3] << 16);
      pk.z = (unsigned)v[4] | ((unsigned)v[5] << 16);
      pk.w = (unsigned)v[6] | ((unsigned)v[7] << 16);
      *(uint4*)(wfrag + (size_t)gid * 8) = pk;
    }
  } else {
    // ---- acts = sigmoid(states+noise) -> padded ci-interleaved bf16 ----
    int idx = (bid - 66) * 512 + tid;          // 532480 exact
    int w4 = idx & 15, h = (idx >> 4) & 63, b = (idx >> 10) & 7, n = idx >> 13;
    int pbase = (n * 8 + b) * CHW + h * 64 + w4 * 4;
    float4 s0 = *(const float4*)(states + pbase);
    float4 s1 = *(const float4*)(states + pbase + IMG);
    float4 s2 = *(const float4*)(states + pbase + 2 * IMG);
    float4 z0 = *(const float4*)(noise + pbase);
    float4 z1 = *(const float4*)(noise + pbase + IMG);
    float4 z2 = *(const float4*)(noise + pbase + 2 * IMG);
    float a0[4], a1[4], a2[4];
    #pragma unroll
    for (int p = 0; p < 4; ++p) {
      float v0 = ((const float*)&s0)[p] + ((const float*)&z0)[p];
      float v1 = ((const float*)&s1)[p] + ((const float*)&z1)[p];
      float v2 = ((const float*)&s2)[p] + ((const float*)&z2)[p];
      a0[p] = 1.0f / (1.0f + __expf(-v0));
      a1[p] = 1.0f / (1.0f + __expf(-v1));
      a2[p] = 1.0f / (1.0f + __expf(-v2));
    }
    uint4 q0, q1;
    q0.x = (unsigned)f2bf(a0[0]) | ((unsigned)f2bf(a1[0]) << 16);
    q0.y = (unsigned)f2bf(a2[0]);
    q0.z = (unsigned)f2bf(a0[1]) | ((unsigned)f2bf(a1[1]) << 16);
    q0.w = (unsigned)f2bf(a2[1]);
    q1.x = (unsigned)f2bf(a0[2]) | ((unsigned)f2bf(a1[2]) << 16);
    q1.y = (unsigned)f2bf(a2[2]);
    q1.z = (unsigned)f2bf(a0[3]) | ((unsigned)f2bf(a1[3]) << 16);
    q1.w = (unsigned)f2bf(a2[3]);
    u16* dp = actsI + (size_t)((n * 8 + b) * ROWS_P + (h + 1)) * 256 + w4 * 16;
    *(uint4*)dp = q0;
    *(uint4*)(dp + 8) = q1;
    uint4 zz; zz.x = 0u; zz.y = 0u; zz.z = 0u; zz.w = 0u;
    if (h == 0) {
      u16* zp = actsI + (size_t)((n * 8 + b) * ROWS_P + 0) * 256 + w4 * 16;
      *(uint4*)zp = zz; *(uint4*)(zp + 8) = zz;
    }
    if (h == 63) {
      u16* zp = actsI + (size_t)((n * 8 + b) * ROWS_P + 65) * 256 + w4 * 16;
      *(uint4*)zp = zz; *(uint4*)(zp + 8) = zz;
      zp += 256;
      *(uint4*)zp = zz; *(uint4*)(zp + 8) = zz;
    }
    if (n == NN) {   // virtual node: out = states (agg is 0 there)
      *(float4*)(out + pbase) = s0;
      *(float4*)(out + pbase + IMG) = s1;
      *(float4*)(out + pbase + 2 * IMG) = s2;
    }
  }
}

// ============ conv: block=(n,b,16 rows), 4 waves share dbuf LDS tile ============
__global__ __launch_bounds__(256, 4) void conv_k(const float* __restrict__ states,
                                                 const float* __restrict__ res,
                                                 const u16* __restrict__ actsI,
                                                 const u16* __restrict__ wfrag,
                                                 const int* __restrict__ csr_off,
                                                 const int2* __restrict__ csr2,
                                                 const float* __restrict__ nodeBias,
                                                 float* __restrict__ out) {
  __shared__ __align__(16) char smem[2 * TILE_B];   // 20064 B

  const int tid = threadIdx.x, lane = tid & 63, wid = tid >> 6;
  const int bid = blockIdx.x;
  const int ht = bid & 3, b = (bid >> 2) & 7, n = bid >> 5;
  const int R0 = ht * 16;

  // staging: 608 x 16B pieces; thread handles pieces tid, tid+256, tid+512
  int pg[3], pl[3];
  #pragma unroll
  for (int j = 0; j < 3; ++j) {
    int p = tid + j * 256;
    int row = p >> 5, c16 = p & 31;
    pg[j] = b * B_STR + (R0 + row) * 256 + c16 * 8;   // u16 units
    pl[j] = row * TROW_B + c16 * 16;                  // bytes
  }
  const bool pv2 = (tid + 512) < NPIECE;

  const int g = lane >> 4, px = lane & 15;
  const int abase = (wid * 4 + g) * TROW_B + px * 8;  // + wr*TROW_B + t*128

  f32x4 acc[4][4];
  #pragma unroll
  for (int wr = 0; wr < 4; ++wr)
    #pragma unroll
    for (int t = 0; t < 4; ++t) { acc[wr][t][0]=0.f; acc[wr][t][1]=0.f; acc[wr][t][2]=0.f; acc[wr][t][3]=0.f; }

  const int e0 = csr_off[n], cnt = csr_off[n + 1] - e0;

  uint4 a0, a1, a2; bf16x8 wa;
  uint4 b0, b1, b2; bf16x8 wb;

#define LOADP(R0_,R1_,R2_,WF_,I_) do {                                        \
    int2 c_ = csr2[e0 + (I_)];                                                \
    int sx_ = __builtin_amdgcn_readfirstlane(c_.x);                           \
    int wx_ = __builtin_amdgcn_readfirstlane(c_.y);                           \
    const u16* ap_ = actsI + sx_;                                             \
    R0_ = *(const uint4*)(ap_ + pg[0]);                                       \
    R1_ = *(const uint4*)(ap_ + pg[1]);                                       \
    if (pv2) R2_ = *(const uint4*)(ap_ + pg[2]);                              \
    WF_ = *(const bf16x8*)(wfrag + wx_ + lane * 8);                           \
  } while (0)

#define STOREP(R0_,R1_,R2_,BUF_) do {                                         \
    *(uint4*)(smem + (BUF_) + pl[0]) = R0_;                                   \
    *(uint4*)(smem + (BUF_) + pl[1]) = R1_;                                   \
    if (pv2) *(uint4*)(smem + (BUF_) + pl[2]) = R2_;                          \
  } while (0)

#define COMP(BUF_,WF_) do {                                                   \
    _Pragma("unroll")                                                         \
    for (int wr_ = 0; wr_ < 4; ++wr_) {                                       \
      _Pragma("unroll")                                                       \
      for (int t_ = 0; t_ < 4; ++t_) {                                        \
        short4 d_ = *(const short4*)(smem + (BUF_) + abase + wr_ * TROW_B + t_ * 128); \
        bf16x8 av_;                                                           \
        av_[0]=d_.x; av_[1]=d_.y; av_[2]=d_.z; av_[3]=d_.w;                   \
        av_[4]=0; av_[5]=0; av_[6]=0; av_[7]=0;                               \
        acc[wr_][t_] = __builtin_amdgcn_mfma_f32_16x16x32_bf16(av_, WF_, acc[wr_][t_], 0, 0, 0); \
      }                                                                       \
    }                                                                         \
  } while (0)

  if (cnt > 0) LOADP(a0, a1, a2, wa, 0);
  if (cnt > 1) LOADP(b0, b1, b2, wb, 1);
  for (int i = 0; i < cnt; i += 2) {
    STOREP(a0, a1, a2, 0);
    bf16x8 wca = wa;
    __syncthreads();                        // tile0 ready; issue next loads AFTER drain
    if (i + 2 < cnt) LOADP(a0, a1, a2, wa, i + 2);
    COMP(0, wca);
    if (i + 1 < cnt) {
      STOREP(b0, b1, b2, TILE_B);
      bf16x8 wcb = wb;
      __syncthreads();
      if (i + 3 < cnt) LOADP(b0, b1, b2, wb, i + 3);
      COMP(TILE_B, wcb);
    }
  }

  // ---- epilogue: per-wave row-at-a-time kw-combine + resistive update ----
  __syncthreads();                          // tiles dead; reuse smem per-wave
  float* zr = (float*)(smem + wid * 3328);  // [64 px][13] f32
  const float bc0 = nodeBias[n * 3 + 0];
  const float bc1 = nodeBias[n * 3 + 1];
  const float bc2 = nodeBias[n * 3 + 2];
  const int col = lane & 15;
  #pragma unroll
  for (int wr = 0; wr < 4; ++wr) {
    if (col < 12) {
      #pragma unroll
      for (int t = 0; t < 4; ++t)
        #pragma unroll
        for (int r = 0; r < 4; ++r)
          zr[(t * 16 + g * 4 + r) * 13 + col] = acc[wr][t][r];
    }
    int hr = R0 + wid * 4 + wr;
    #pragma unroll
    for (int co = 0; co < 3; ++co) {
      float y = (co == 0) ? bc0 : ((co == 1) ? bc1 : bc2);
      #pragma unroll
      for (int kw = 0; kw < 4; ++kw) {
        int wp = lane + kw - 1;
        if (wp >= 0 && wp < 64) y += zr[wp * 13 + co * 4 + kw];
      }
      int o = ((n * 8 + b) * 3 + co) * IMG + hr * 64 + lane;
      float st = states[o];
      out[o] = st + fabsf(res[o]) * (EQF - st) + y;
    }
  }
}

extern "C" void kernel_launch(void* const* d_in, const int* in_sizes, int n_in,
                              void* d_out, int out_size, void* d_ws, size_t ws_size,
                              hipStream_t stream) {
  const float* states = (const float*)d_in[0];
  const float* noise  = (const float*)d_in[1];
  const float* conv_w = (const float*)d_in[2];
  const float* conv_b = (const float*)d_in[3];
  const float* res    = (const float*)d_in[4];
  const int*   src    = (const int*)d_in[5];
  const int*   dst    = (const int*)d_in[6];
  float* out = (float*)d_out;

  u16* actsI = (u16*)d_ws;                                   // 17,838,080 B
  u16* wfrag = (u16*)((char*)d_ws + 17838080);               // 525,312 B -> 18,363,392
  int* csr_off = (int*)((char*)d_ws + 18363392);             // 320 B -> 18,363,712
  int2* csr2 = (int2*)((char*)d_ws + 18363712);              // 4,104 B -> 18,367,816
  float* nodeBias = (float*)((char*)d_ws + 18367816);        // 768 B

  pre_k<<<1106, 512, 0, stream>>>(conv_w, conv_b, src, dst, states, noise,
                                  actsI, wfrag, csr_off, csr2, nodeBias, out);
  conv_k<<<2048, 256, 0, stream>>>(states, res, actsI, wfrag, csr_off, csr2, nodeBias, out);
}